// Round 1
// baseline (363.891 us; speedup 1.0000x reference)
//
#include <hip/hip_runtime.h>
#include <hip/hip_bf16.h>
#include <math.h>

// ---------------------------------------------------------------------------
// Stage 1: h = tanh(x @ W^T + b_lin), fused per-row inv-norm.
// Block = 256 threads = 4 waves; block handles 16 rows (4 rows/wave).
// W staged in LDS in K-chunks of 32 (pad stride 34 floats -> bank (2d+k)%32,
// balanced for b64 reads). x rows staged in LDS, read wave-uniform (broadcast).
// Each lane owns d = lane and d = lane+64 for its wave's 4 rows.
// ---------------------------------------------------------------------------
__global__ __launch_bounds__(256) void k_gemm_tanh(
    const float* __restrict__ x, const float* __restrict__ W,
    const float* __restrict__ bl, float* __restrict__ h,
    float* __restrict__ inv_norm) {
  __shared__ float ws[128 * 34];   // 17408 B
  __shared__ float xs[16 * 128];   // 8192 B
  const int tid = threadIdx.x;
  const int wv = tid >> 6, lane = tid & 63;
  const int nbase = blockIdx.x * 16;

  // stage 16 x-rows (2048 floats) coalesced as float4
  {
    const float4* xg = (const float4*)(x + (size_t)nbase * 128);
    float4* xs4 = (float4*)xs;
    for (int i = tid; i < 16 * 32; i += 256) xs4[i] = xg[i];
  }

  float acc[4][2] = {};
  const float2* wg = (const float2*)W;
  for (int kc = 0; kc < 4; ++kc) {
    __syncthreads();  // protect ws reuse (and xs stores on first pass)
    // stage W[:, kc*32 : kc*32+32] -> ws[d*34 + k]
    for (int i = tid; i < 2048; i += 256) {
      int d = i >> 4;
      int kk = i & 15;  // float2 index within 32-wide chunk
      float2 v = wg[d * 64 + kc * 16 + kk];
      *(float2*)&ws[d * 34 + kk * 2] = v;
    }
    __syncthreads();
    const float* xrow = &xs[(wv * 4) * 128 + kc * 32];
#pragma unroll
    for (int k = 0; k < 32; k += 2) {
      float2 w1 = *(const float2*)&ws[lane * 34 + k];
      float2 w2 = *(const float2*)&ws[(lane + 64) * 34 + k];
#pragma unroll
      for (int r = 0; r < 4; ++r) {
        float xa = xrow[r * 128 + k];      // wave-uniform -> LDS broadcast
        float xb = xrow[r * 128 + k + 1];
        acc[r][0] = fmaf(xb, w1.y, fmaf(xa, w1.x, acc[r][0]));
        acc[r][1] = fmaf(xb, w2.y, fmaf(xa, w2.x, acc[r][1]));
      }
    }
  }

  const float b1 = bl[lane], b2 = bl[lane + 64];
  const int n0 = nbase + wv * 4;
#pragma unroll
  for (int r = 0; r < 4; ++r) {
    float t1 = tanhf(acc[r][0] + b1);
    float t2 = tanhf(acc[r][1] + b2);
    h[(size_t)(n0 + r) * 128 + lane] = t1;
    h[(size_t)(n0 + r) * 128 + lane + 64] = t2;
    float ss = t1 * t1 + t2 * t2;
#pragma unroll
    for (int off = 32; off; off >>= 1) ss += __shfl_xor(ss, off);
    if (lane == 0) inv_norm[n0 + r] = 1.0f / fmaxf(sqrtf(ss), 1e-8f);
  }
}

// ---------------------------------------------------------------------------
// Stage 2: edge cosine similarity -> relu -> edge_weights (written straight
// into d_out's second slice). 16 lanes per edge, 2x float4 per lane per vec.
// ---------------------------------------------------------------------------
__global__ __launch_bounds__(256) void k_edge_cos(
    const float* __restrict__ h, const float* __restrict__ inv_norm,
    const int* __restrict__ rows, const int* __restrict__ cols,
    float* __restrict__ ew, int E) {
  int e = (blockIdx.x * 256 + threadIdx.x) >> 4;
  int sub = threadIdx.x & 15;
  if (e >= E) return;
  int r = rows[e], c = cols[e];
  const float4* hr = (const float4*)(h + (size_t)r * 128);
  const float4* hc = (const float4*)(h + (size_t)c * 128);
  float4 a0 = hr[sub], a1 = hr[sub + 16];
  float4 b0 = hc[sub], b1 = hc[sub + 16];
  float dot = a0.x * b0.x + a0.y * b0.y + a0.z * b0.z + a0.w * b0.w +
              a1.x * b1.x + a1.y * b1.y + a1.z * b1.z + a1.w * b1.w;
#pragma unroll
  for (int off = 8; off; off >>= 1) dot += __shfl_xor(dot, off);
  if (sub == 0) {
    float cosv = dot * inv_norm[r] * inv_norm[c];
    ew[e] = fmaxf(cosv, 0.0f);
  }
}

// ---------------------------------------------------------------------------
// Degree / normalization / propagation-prep kernels (feature dim = 1).
// ---------------------------------------------------------------------------
__global__ void k_deg_init(float* __restrict__ deg, int N) {
  int n = blockIdx.x * 256 + threadIdx.x;
  if (n < N) deg[n] = 1.0f;  // self-loop weight
}

__global__ void k_deg_scatter(const int* __restrict__ cols,
                              const float* __restrict__ ew,
                              float* __restrict__ deg, int E) {
  int e = blockIdx.x * 256 + threadIdx.x;
  if (e < E) atomicAdd(deg + cols[e], ew[e]);
}

// dinv, self-loop norm, h0=relu(mask), f=h0, agg = self_norm*h0
__global__ void k_prep(const float* __restrict__ deg,
                       const float* __restrict__ mask,
                       float* __restrict__ dinv, float* __restrict__ self_norm,
                       float* __restrict__ h0, float* __restrict__ f,
                       float* __restrict__ agg, int N) {
  int n = blockIdx.x * 256 + threadIdx.x;
  if (n >= N) return;
  float d = deg[n];
  float di = (d > 0.0f) ? 1.0f / sqrtf(d) : 0.0f;
  dinv[n] = di;
  float sn = di * di;
  self_norm[n] = sn;
  float h0v = fmaxf(mask[n], 0.0f);
  h0[n] = h0v;
  f[n] = h0v;
  agg[n] = sn * h0v;
}

__global__ void k_norm_e(const int* __restrict__ rows,
                         const int* __restrict__ cols,
                         const float* __restrict__ ew,
                         const float* __restrict__ dinv,
                         float* __restrict__ norm_e, int E) {
  int e = blockIdx.x * 256 + threadIdx.x;
  if (e < E) norm_e[e] = dinv[rows[e]] * ew[e] * dinv[cols[e]];
}

__global__ void k_scatter(const int* __restrict__ rows,
                          const int* __restrict__ cols,
                          const float* __restrict__ norm_e,
                          const float* __restrict__ f,
                          float* __restrict__ agg, int E) {
  int e = blockIdx.x * 256 + threadIdx.x;
  if (e < E) atomicAdd(agg + cols[e], norm_e[e] * f[rows[e]]);
}

// f_new = (1-alpha)*agg + alpha*h0 ; non-last: agg := self_norm*f_new (prep
// next iteration); last: fill = tanh(f_new - softplus(bias)) -> d_out.
__global__ void k_update(float* __restrict__ f, float* __restrict__ agg,
                         const float* __restrict__ h0,
                         const float* __restrict__ self_norm,
                         const float* __restrict__ alpha_p,
                         const float* __restrict__ bias_p,
                         float* __restrict__ fill, int N, int last) {
  int n = blockIdx.x * 256 + threadIdx.x;
  if (n >= N) return;
  float a = alpha_p[0];
  float fn = (1.0f - a) * agg[n] + a * h0[n];
  if (last) {
    float b = bias_p[0];
    float sp = (b > 20.0f) ? b : log1pf(expf(b));
    fill[n] = tanhf(fn - sp);
  } else {
    f[n] = fn;
    agg[n] = self_norm[n] * fn;
  }
}

// ---------------------------------------------------------------------------
extern "C" void kernel_launch(void* const* d_in, const int* in_sizes, int n_in,
                              void* d_out, int out_size, void* d_ws,
                              size_t ws_size, hipStream_t stream) {
  const float* x = (const float*)d_in[0];
  const float* mask = (const float*)d_in[1];
  const int* ei = (const int*)d_in[2];  // [2, E] int32 (jax x64 disabled)
  const float* W = (const float*)d_in[3];
  const float* bl = (const float*)d_in[4];
  const float* alpha = (const float*)d_in[5];
  const float* bias = (const float*)d_in[6];

  const int D = 128;
  const int N = in_sizes[0] / D;  // 50000
  const int E = in_sizes[2] / 2;  // 600000
  const int* rows = ei;
  const int* cols = ei + E;

  float* fill = (float*)d_out;        // [N]
  float* ew = (float*)d_out + N;      // [E] edge_weights output slice

  // workspace carve-up (256B aligned)
  char* w = (char*)d_ws;
  size_t off = 0;
  auto alloc = [&](size_t bytes) -> float* {
    float* p = (float*)(w + off);
    off = (off + bytes + 255) & ~(size_t)255;
    return p;
  };
  float* h = alloc((size_t)N * D * sizeof(float));  // 25.6 MB
  float* inv_norm = alloc((size_t)N * sizeof(float));
  float* deg = alloc((size_t)N * sizeof(float));
  float* dinv = alloc((size_t)N * sizeof(float));
  float* self_norm = alloc((size_t)N * sizeof(float));
  float* h0 = alloc((size_t)N * sizeof(float));
  float* f = alloc((size_t)N * sizeof(float));
  float* agg = alloc((size_t)N * sizeof(float));
  float* norm_e = alloc((size_t)E * sizeof(float));
  (void)ws_size;

  const int nb_N = (N + 255) / 256;
  const int nb_E = (E + 255) / 256;

  // 1. GEMM + tanh + row inv-norms (N divisible by 16)
  k_gemm_tanh<<<N / 16, 256, 0, stream>>>(x, W, bl, h, inv_norm);
  // 2. edge cosine -> edge_weights (d_out slice)
  k_edge_cos<<<(E * 16 + 255) / 256, 256, 0, stream>>>(h, inv_norm, rows, cols,
                                                       ew, E);
  // 3. degrees (self-loop = 1 + scatter of edge weights by col)
  k_deg_init<<<nb_N, 256, 0, stream>>>(deg, N);
  k_deg_scatter<<<nb_E, 256, 0, stream>>>(cols, ew, deg, E);
  // 4. dinv / self_norm / h0 / f / agg init
  k_prep<<<nb_N, 256, 0, stream>>>(deg, mask, dinv, self_norm, h0, f, agg, N);
  // 5. per-edge norms
  k_norm_e<<<nb_E, 256, 0, stream>>>(rows, cols, ew, dinv, norm_e, E);
  // 6. K=5 APPNP iterations
  for (int it = 0; it < 5; ++it) {
    k_scatter<<<nb_E, 256, 0, stream>>>(rows, cols, norm_e, f, agg, E);
    k_update<<<nb_N, 256, 0, stream>>>(f, agg, h0, self_norm, alpha, bias,
                                       fill, N, it == 4 ? 1 : 0);
  }
}

// Round 2
// 318.641 us; speedup vs baseline: 1.1420x; 1.1420x over previous
//
#include <hip/hip_runtime.h>
#include <hip/hip_bf16.h>
#include <hip/hip_fp16.h>
#include <math.h>

// ---------------------------------------------------------------------------
// Stage 1: h = tanh(x @ W^T + b_lin), row-normalized, stored as fp16.
// (cosine similarity is scale-invariant, so we fold the inv-norm in here and
// the edge kernel becomes a plain dot product at half the gather bytes.)
// Block = 256 threads = 4 waves; block handles 16 rows (4 rows/wave).
// Also initializes deg[n] = 1.0 (self-loop weight) to save a launch.
// ---------------------------------------------------------------------------
__global__ __launch_bounds__(256) void k_gemm_tanh(
    const float* __restrict__ x, const float* __restrict__ W,
    const float* __restrict__ bl, __half* __restrict__ hn,
    float* __restrict__ deg) {
  __shared__ float ws[128 * 34];   // 17408 B
  __shared__ float xs[16 * 128];   // 8192 B
  const int tid = threadIdx.x;
  const int wv = tid >> 6, lane = tid & 63;
  const int nbase = blockIdx.x * 16;

  if (tid < 16) deg[nbase + tid] = 1.0f;  // self-loop init

  // stage 16 x-rows (2048 floats) coalesced as float4
  {
    const float4* xg = (const float4*)(x + (size_t)nbase * 128);
    float4* xs4 = (float4*)xs;
    for (int i = tid; i < 16 * 32; i += 256) xs4[i] = xg[i];
  }

  float acc[4][2] = {};
  const float2* wg = (const float2*)W;
  for (int kc = 0; kc < 4; ++kc) {
    __syncthreads();  // protect ws reuse (and xs stores on first pass)
    // stage W[:, kc*32 : kc*32+32] -> ws[d*34 + k]
    for (int i = tid; i < 2048; i += 256) {
      int d = i >> 4;
      int kk = i & 15;  // float2 index within 32-wide chunk
      float2 v = wg[d * 64 + kc * 16 + kk];
      *(float2*)&ws[d * 34 + kk * 2] = v;
    }
    __syncthreads();
    const float2* xr2 = (const float2*)&xs[(wv * 4) * 128 + kc * 32];
#pragma unroll
    for (int k2 = 0; k2 < 16; ++k2) {
      float2 w1 = *(const float2*)&ws[lane * 34 + k2 * 2];
      float2 w2 = *(const float2*)&ws[(lane + 64) * 34 + k2 * 2];
#pragma unroll
      for (int r = 0; r < 4; ++r) {
        float2 xv = xr2[r * 64 + k2];  // wave-uniform -> LDS broadcast
        acc[r][0] = fmaf(xv.y, w1.y, fmaf(xv.x, w1.x, acc[r][0]));
        acc[r][1] = fmaf(xv.y, w2.y, fmaf(xv.x, w2.x, acc[r][1]));
      }
    }
  }

  const float b1 = bl[lane], b2 = bl[lane + 64];
  const int n0 = nbase + wv * 4;
#pragma unroll
  for (int r = 0; r < 4; ++r) {
    float t1 = tanhf(acc[r][0] + b1);
    float t2 = tanhf(acc[r][1] + b2);
    float ss = t1 * t1 + t2 * t2;
#pragma unroll
    for (int off = 32; off; off >>= 1) ss += __shfl_xor(ss, off);
    float inv = 1.0f / fmaxf(sqrtf(ss), 1e-8f);
    hn[(size_t)(n0 + r) * 128 + lane] = __float2half_rn(t1 * inv);
    hn[(size_t)(n0 + r) * 128 + lane + 64] = __float2half_rn(t2 * inv);
  }
}

// ---------------------------------------------------------------------------
// Stage 2: edge cosine = dot of normalized fp16 rows -> relu -> ew.
// 8 lanes per edge; each lane loads 2x float4 (=16 halves) from each row.
// ---------------------------------------------------------------------------
__device__ __forceinline__ float dot8h(float4 a, float4 b) {
  const __half2* pa = (const __half2*)&a;
  const __half2* pb = (const __half2*)&b;
  float s = 0.0f;
#pragma unroll
  for (int i = 0; i < 4; ++i) {
    float2 fa = __half22float2(pa[i]);
    float2 fb = __half22float2(pb[i]);
    s = fmaf(fa.x, fb.x, s);
    s = fmaf(fa.y, fb.y, s);
  }
  return s;
}

__global__ __launch_bounds__(256) void k_edge_cos(
    const __half* __restrict__ hn, const int* __restrict__ rows,
    const int* __restrict__ cols, float* __restrict__ ew, int E) {
  int t = blockIdx.x * 256 + threadIdx.x;
  int e = t >> 3, sub = t & 7;
  if (e >= E) return;
  int r = rows[e], c = cols[e];
  const float4* hr = (const float4*)(hn + (size_t)r * 128);  // 16 float4/row
  const float4* hc = (const float4*)(hn + (size_t)c * 128);
  float4 a0 = hr[sub], a1 = hr[sub + 8];
  float4 b0 = hc[sub], b1 = hc[sub + 8];
  float dot = dot8h(a0, b0) + dot8h(a1, b1);
#pragma unroll
  for (int off = 4; off; off >>= 1) dot += __shfl_xor(dot, off);
  if (sub == 0) ew[e] = fmaxf(dot, 0.0f);
}

// ---------------------------------------------------------------------------
// Propagation kernels (feature dim = 1).
// ---------------------------------------------------------------------------
__global__ void k_deg_scatter(const int* __restrict__ cols,
                              const float* __restrict__ ew,
                              float* __restrict__ deg, int E) {
  int e = blockIdx.x * 256 + threadIdx.x;
  if (e < E) atomicAdd(deg + cols[e], ew[e]);
}

// Fused: per-node prep (self_norm, h0, f, agg init) + per-edge norm.
// deg >= 1 always (self-loop), so dinv = rsqrt(deg) unconditionally.
__global__ void k_prep_norm(const int* __restrict__ rows,
                            const int* __restrict__ cols,
                            const float* __restrict__ ew,
                            const float* __restrict__ deg,
                            const float* __restrict__ mask,
                            float* __restrict__ self_norm,
                            float* __restrict__ h0, float* __restrict__ f,
                            float* __restrict__ agg,
                            float* __restrict__ norm_e, int N, int E) {
  int i = blockIdx.x * 256 + threadIdx.x;
  if (i < N) {
    float d = deg[i];
    float sn = 1.0f / d;  // dinv^2
    self_norm[i] = sn;
    float h0v = fmaxf(mask[i], 0.0f);
    h0[i] = h0v;
    f[i] = h0v;
    agg[i] = sn * h0v;  // self-loop contribution for iteration 0
  }
  if (i < E) {
    float dr = deg[rows[i]], dc = deg[cols[i]];
    norm_e[i] = ew[i] * rsqrtf(dr) * rsqrtf(dc);
  }
}

__global__ void k_scatter(const int* __restrict__ rows,
                          const int* __restrict__ cols,
                          const float* __restrict__ norm_e,
                          const float* __restrict__ f,
                          float* __restrict__ agg, int E) {
  int e = blockIdx.x * 256 + threadIdx.x;
  if (e < E) atomicAdd(agg + cols[e], norm_e[e] * f[rows[e]]);
}

// f_new = (1-alpha)*agg + alpha*h0 ; non-last: agg := self_norm*f_new (prep
// next iteration); last: fill = tanh(f_new - softplus(bias)) -> d_out.
__global__ void k_update(float* __restrict__ f, float* __restrict__ agg,
                         const float* __restrict__ h0,
                         const float* __restrict__ self_norm,
                         const float* __restrict__ alpha_p,
                         const float* __restrict__ bias_p,
                         float* __restrict__ fill, int N, int last) {
  int n = blockIdx.x * 256 + threadIdx.x;
  if (n >= N) return;
  float a = alpha_p[0];
  float fn = (1.0f - a) * agg[n] + a * h0[n];
  if (last) {
    float b = bias_p[0];
    float sp = (b > 20.0f) ? b : log1pf(expf(b));
    fill[n] = tanhf(fn - sp);
  } else {
    f[n] = fn;
    agg[n] = self_norm[n] * fn;
  }
}

// ---------------------------------------------------------------------------
extern "C" void kernel_launch(void* const* d_in, const int* in_sizes, int n_in,
                              void* d_out, int out_size, void* d_ws,
                              size_t ws_size, hipStream_t stream) {
  const float* x = (const float*)d_in[0];
  const float* mask = (const float*)d_in[1];
  const int* ei = (const int*)d_in[2];  // [2, E] int32 (jax x64 disabled)
  const float* W = (const float*)d_in[3];
  const float* bl = (const float*)d_in[4];
  const float* alpha = (const float*)d_in[5];
  const float* bias = (const float*)d_in[6];

  const int D = 128;
  const int N = in_sizes[0] / D;  // 50000
  const int E = in_sizes[2] / 2;  // 600000
  const int* rows = ei;
  const int* cols = ei + E;

  float* fill = (float*)d_out;    // [N]
  float* ew = (float*)d_out + N;  // [E] edge_weights output slice

  // workspace carve-up (256B aligned)
  char* w = (char*)d_ws;
  size_t off = 0;
  auto alloc = [&](size_t bytes) -> void* {
    void* p = (void*)(w + off);
    off = (off + bytes + 255) & ~(size_t)255;
    return p;
  };
  __half* hn = (__half*)alloc((size_t)N * D * sizeof(__half));  // 12.8 MB
  float* deg = (float*)alloc((size_t)N * sizeof(float));
  float* self_norm = (float*)alloc((size_t)N * sizeof(float));
  float* h0 = (float*)alloc((size_t)N * sizeof(float));
  float* f = (float*)alloc((size_t)N * sizeof(float));
  float* agg = (float*)alloc((size_t)N * sizeof(float));
  float* norm_e = (float*)alloc((size_t)E * sizeof(float));
  (void)ws_size;

  const int nb_N = (N + 255) / 256;
  const int nb_E = (E + 255) / 256;

  // 1. GEMM + tanh + normalize + fp16 store (+ deg=1 init)
  k_gemm_tanh<<<N / 16, 256, 0, stream>>>(x, W, bl, hn, deg);
  // 2. edge cosine -> edge_weights (d_out slice)
  k_edge_cos<<<(E * 8 + 255) / 256, 256, 0, stream>>>(hn, rows, cols, ew, E);
  // 3. degree scatter (self-loop already in deg)
  k_deg_scatter<<<nb_E, 256, 0, stream>>>(cols, ew, deg, E);
  // 4. fused node-prep + per-edge norm
  k_prep_norm<<<nb_E, 256, 0, stream>>>(rows, cols, ew, deg, mask, self_norm,
                                        h0, f, agg, norm_e, N, E);
  // 5. K=5 APPNP iterations
  for (int it = 0; it < 5; ++it) {
    k_scatter<<<nb_E, 256, 0, stream>>>(rows, cols, norm_e, f, agg, E);
    k_update<<<nb_N, 256, 0, stream>>>(f, agg, h0, self_norm, alpha, bias,
                                       fill, N, it == 4 ? 1 : 0);
  }
}

// Round 3
// 298.702 us; speedup vs baseline: 1.2182x; 1.0668x over previous
//
#include <hip/hip_runtime.h>
#include <hip/hip_bf16.h>
#include <hip/hip_fp16.h>
#include <math.h>

typedef _Float16 half8 __attribute__((ext_vector_type(8)));
typedef float f32x4 __attribute__((ext_vector_type(4)));

// ---------------------------------------------------------------------------
// W fp32 [128][128] -> f16 [128][128] (row-major, same layout). 32 KB result
// is L1-resident for the GEMM kernel.
// ---------------------------------------------------------------------------
__global__ void k_conv_w(const float* __restrict__ W,
                         _Float16* __restrict__ Wh) {
  int i = blockIdx.x * 256 + threadIdx.x;  // 16384 elems / 4 per thread
  float4 v = ((const float4*)W)[i];
  _Float16 o[4] = {(_Float16)v.x, (_Float16)v.y, (_Float16)v.z, (_Float16)v.w};
  *(short4*)((short*)Wh + i * 4) = *(short4*)o;
}

// ---------------------------------------------------------------------------
// Stage 1 (MFMA): h = tanh(x @ W^T + b_lin), row-normalized, stored fp16.
// 4 waves/block, each wave: 16 rows x 128 cols via mfma_f32_16x16x32_f16.
// A: lane holds x[row0 + (l&15)][ks*32 + (l>>4)*8 .. +7] (fp32->f16 in reg).
// B: lane holds Wh[c*16 + (l&15)][ks*32 + (l>>4)*8 .. +7] (16B load, L1-hot).
// C: col = l&15, row = (l>>4)*4 + reg  [verified m89/m91 mapping].
// Also initializes deg[n] = 1.0 (self-loop weight).
// ---------------------------------------------------------------------------
__global__ __launch_bounds__(256) void k_gemm_mfma(
    const float* __restrict__ x, const _Float16* __restrict__ Wh,
    const float* __restrict__ bl, __half* __restrict__ hn,
    float* __restrict__ deg, int N) {
  const int wv = threadIdx.x >> 6, lane = threadIdx.x & 63;
  const int nb = blockIdx.x * 64;
  if (threadIdx.x < 64 && nb + threadIdx.x < N) deg[nb + threadIdx.x] = 1.0f;
  const int row0 = nb + wv * 16;
  if (row0 >= N) return;  // tail block: waves past the end (N % 16 == 0)

  const int r = lane & 15;   // A-row / B-col / C-col within tile
  const int g = lane >> 4;   // k-group (operands), row-group (C)

  // A fragments for 4 k-steps (32 floats -> 32 halves in-reg)
  half8 afrag[4];
  {
    const float4* xr = (const float4*)(x + (size_t)(row0 + r) * 128);
#pragma unroll
    for (int ks = 0; ks < 4; ++ks) {
      float4 lo = xr[ks * 8 + g * 2];
      float4 hi = xr[ks * 8 + g * 2 + 1];
      half8 a;
      a[0] = (_Float16)lo.x; a[1] = (_Float16)lo.y;
      a[2] = (_Float16)lo.z; a[3] = (_Float16)lo.w;
      a[4] = (_Float16)hi.x; a[5] = (_Float16)hi.y;
      a[6] = (_Float16)hi.z; a[7] = (_Float16)hi.w;
      afrag[ks] = a;
    }
  }

  f32x4 acc[8];
#pragma unroll
  for (int c = 0; c < 8; ++c) acc[c] = (f32x4){0.f, 0.f, 0.f, 0.f};
#pragma unroll
  for (int c = 0; c < 8; ++c) {
    const _Float16* wrow = Wh + (size_t)(c * 16 + r) * 128 + g * 8;
#pragma unroll
    for (int ks = 0; ks < 4; ++ks) {
      half8 b = *(const half8*)(wrow + ks * 32);
      acc[c] = __builtin_amdgcn_mfma_f32_16x16x32_f16(afrag[ks], b, acc[c],
                                                      0, 0, 0);
    }
  }

  // epilogue: bias + tanh, row sum-of-squares, normalize, fp16 store
  float t[8][4];
  float ss[4] = {0.f, 0.f, 0.f, 0.f};
#pragma unroll
  for (int c = 0; c < 8; ++c) {
    float bv = bl[c * 16 + r];
#pragma unroll
    for (int j = 0; j < 4; ++j) {
      float tv = tanhf(acc[c][j] + bv);
      t[c][j] = tv;
      ss[j] = fmaf(tv, tv, ss[j]);
    }
  }
#pragma unroll
  for (int j = 0; j < 4; ++j) {
#pragma unroll
    for (int off = 8; off; off >>= 1) ss[j] += __shfl_xor(ss[j], off);
    ss[j] = 1.0f / fmaxf(sqrtf(ss[j]), 1e-8f);
  }
#pragma unroll
  for (int c = 0; c < 8; ++c)
#pragma unroll
    for (int j = 0; j < 4; ++j)
      hn[(size_t)(row0 + g * 4 + j) * 128 + c * 16 + r] =
          __float2half_rn(t[c][j] * ss[j]);
}

// ---------------------------------------------------------------------------
// Stage 2: edge cosine = dot of normalized fp16 rows -> relu -> ew.
// 8 lanes per edge; each lane loads 2x float4 (=16 halves) from each row.
// ---------------------------------------------------------------------------
__device__ __forceinline__ float dot8h(float4 a, float4 b) {
  const __half2* pa = (const __half2*)&a;
  const __half2* pb = (const __half2*)&b;
  float s = 0.0f;
#pragma unroll
  for (int i = 0; i < 4; ++i) {
    float2 fa = __half22float2(pa[i]);
    float2 fb = __half22float2(pb[i]);
    s = fmaf(fa.x, fb.x, s);
    s = fmaf(fa.y, fb.y, s);
  }
  return s;
}

__global__ __launch_bounds__(256) void k_edge_cos(
    const __half* __restrict__ hn, const int* __restrict__ rows,
    const int* __restrict__ cols, float* __restrict__ ew, int E) {
  int t = blockIdx.x * 256 + threadIdx.x;
  int e = t >> 3, sub = t & 7;
  if (e >= E) return;
  int r = rows[e], c = cols[e];
  const float4* hr = (const float4*)(hn + (size_t)r * 128);  // 16 float4/row
  const float4* hc = (const float4*)(hn + (size_t)c * 128);
  float4 a0 = hr[sub], a1 = hr[sub + 8];
  float4 b0 = hc[sub], b1 = hc[sub + 8];
  float dot = dot8h(a0, b0) + dot8h(a1, b1);
#pragma unroll
  for (int off = 4; off; off >>= 1) dot += __shfl_xor(dot, off);
  if (sub == 0) ew[e] = fmaxf(dot, 0.0f);
}

// ---------------------------------------------------------------------------
// Propagation kernels (feature dim = 1).
// ---------------------------------------------------------------------------
__global__ void k_deg_scatter(const int* __restrict__ cols,
                              const float* __restrict__ ew,
                              float* __restrict__ deg, int E) {
  int e = blockIdx.x * 256 + threadIdx.x;
  if (e < E) atomicAdd(deg + cols[e], ew[e]);
}

// Fused: per-node prep (self_norm, h0, f, agg init) + per-edge norm.
// deg >= 1 always (self-loop), so dinv = rsqrt(deg) unconditionally.
__global__ void k_prep_norm(const int* __restrict__ rows,
                            const int* __restrict__ cols,
                            const float* __restrict__ ew,
                            const float* __restrict__ deg,
                            const float* __restrict__ mask,
                            float* __restrict__ self_norm,
                            float* __restrict__ h0, float* __restrict__ f,
                            float* __restrict__ agg,
                            float* __restrict__ norm_e, int N, int E) {
  int i = blockIdx.x * 256 + threadIdx.x;
  if (i < N) {
    float d = deg[i];
    float sn = 1.0f / d;  // dinv^2
    self_norm[i] = sn;
    float h0v = fmaxf(mask[i], 0.0f);
    h0[i] = h0v;
    f[i] = h0v;
    agg[i] = sn * h0v;  // self-loop contribution for iteration 0
  }
  if (i < E) {
    float dr = deg[rows[i]], dc = deg[cols[i]];
    norm_e[i] = ew[i] * rsqrtf(dr) * rsqrtf(dc);
  }
}

__global__ void k_scatter(const int* __restrict__ rows,
                          const int* __restrict__ cols,
                          const float* __restrict__ norm_e,
                          const float* __restrict__ f,
                          float* __restrict__ agg, int E) {
  int e = blockIdx.x * 256 + threadIdx.x;
  if (e < E) atomicAdd(agg + cols[e], norm_e[e] * f[rows[e]]);
}

// f_new = (1-alpha)*agg + alpha*h0 ; non-last: agg := self_norm*f_new (prep
// next iteration); last: fill = tanh(f_new - softplus(bias)) -> d_out.
__global__ void k_update(float* __restrict__ f, float* __restrict__ agg,
                         const float* __restrict__ h0,
                         const float* __restrict__ self_norm,
                         const float* __restrict__ alpha_p,
                         const float* __restrict__ bias_p,
                         float* __restrict__ fill, int N, int last) {
  int n = blockIdx.x * 256 + threadIdx.x;
  if (n >= N) return;
  float a = alpha_p[0];
  float fn = (1.0f - a) * agg[n] + a * h0[n];
  if (last) {
    float b = bias_p[0];
    float sp = (b > 20.0f) ? b : log1pf(expf(b));
    fill[n] = tanhf(fn - sp);
  } else {
    f[n] = fn;
    agg[n] = self_norm[n] * fn;
  }
}

// ---------------------------------------------------------------------------
extern "C" void kernel_launch(void* const* d_in, const int* in_sizes, int n_in,
                              void* d_out, int out_size, void* d_ws,
                              size_t ws_size, hipStream_t stream) {
  const float* x = (const float*)d_in[0];
  const float* mask = (const float*)d_in[1];
  const int* ei = (const int*)d_in[2];  // [2, E] int32 (jax x64 disabled)
  const float* W = (const float*)d_in[3];
  const float* bl = (const float*)d_in[4];
  const float* alpha = (const float*)d_in[5];
  const float* bias = (const float*)d_in[6];

  const int D = 128;
  const int N = in_sizes[0] / D;  // 50000
  const int E = in_sizes[2] / 2;  // 600000
  const int* rows = ei;
  const int* cols = ei + E;

  float* fill = (float*)d_out;    // [N]
  float* ew = (float*)d_out + N;  // [E] edge_weights output slice

  // workspace carve-up (256B aligned)
  char* w = (char*)d_ws;
  size_t off = 0;
  auto alloc = [&](size_t bytes) -> void* {
    void* p = (void*)(w + off);
    off = (off + bytes + 255) & ~(size_t)255;
    return p;
  };
  __half* hn = (__half*)alloc((size_t)N * D * sizeof(__half));  // 12.8 MB
  _Float16* Wh = (_Float16*)alloc((size_t)D * D * sizeof(_Float16));
  float* deg = (float*)alloc((size_t)N * sizeof(float));
  float* self_norm = (float*)alloc((size_t)N * sizeof(float));
  float* h0 = (float*)alloc((size_t)N * sizeof(float));
  float* f = (float*)alloc((size_t)N * sizeof(float));
  float* agg = (float*)alloc((size_t)N * sizeof(float));
  float* norm_e = (float*)alloc((size_t)E * sizeof(float));
  (void)ws_size;

  const int nb_N = (N + 255) / 256;
  const int nb_E = (E + 255) / 256;

  // 0. W -> f16
  k_conv_w<<<16, 256, 0, stream>>>(W, Wh);
  // 1. MFMA GEMM + tanh + normalize + fp16 store (+ deg=1 init)
  k_gemm_mfma<<<(N + 63) / 64, 256, 0, stream>>>(x, Wh, bl, hn, deg, N);
  // 2. edge cosine -> edge_weights (d_out slice)
  k_edge_cos<<<(E * 8 + 255) / 256, 256, 0, stream>>>(hn, rows, cols, ew, E);
  // 3. degree scatter (self-loop already in deg)
  k_deg_scatter<<<nb_E, 256, 0, stream>>>(cols, ew, deg, E);
  // 4. fused node-prep + per-edge norm
  k_prep_norm<<<nb_E, 256, 0, stream>>>(rows, cols, ew, deg, mask, self_norm,
                                        h0, f, agg, norm_e, N, E);
  // 5. K=5 APPNP iterations
  for (int it = 0; it < 5; ++it) {
    k_scatter<<<nb_E, 256, 0, stream>>>(rows, cols, norm_e, f, agg, E);
    k_update<<<nb_N, 256, 0, stream>>>(f, agg, h0, self_norm, alpha, bias,
                                       fill, N, it == 4 ? 1 : 0);
  }
}

// Round 4
// 253.576 us; speedup vs baseline: 1.4350x; 1.1780x over previous
//
#include <hip/hip_runtime.h>
#include <hip/hip_bf16.h>
#include <hip/hip_fp16.h>
#include <math.h>

typedef _Float16 half8 __attribute__((ext_vector_type(8)));
typedef float f32x4 __attribute__((ext_vector_type(4)));

__device__ __forceinline__ float tanh_fast(float v) {
  // tanh(v) = 1 - 2/(exp(2v)+1); saturates correctly (exp->inf => 1, ->0 => -1)
  float e = __expf(v + v);
  return 1.0f - 2.0f * __builtin_amdgcn_rcpf(e + 1.0f);
}

// ---------------------------------------------------------------------------
// Stage 1 (MFMA): h = tanh(x @ W^T + b_lin), row-normalized, stored fp16.
// W is converted fp32->f16 into a 32KB XOR-swizzled LDS tile per block
// (byte ^= (row&7)<<4 within the 256B row -> ds_read_b128 is conflict-free;
// linear layout would be a 16-way conflict, G4's D=128 case).
// 4 waves/block, each wave: 16 rows x 128 cols via mfma_f32_16x16x32_f16.
// A: lane holds x[row0 + (l&15)][(l>>4)*8 + ks*32 ..+7] (fp32->f16 in reg).
// B: lane holds W[c*16 + (l&15)][(l>>4)*8 + ks*32 ..+7] from LDS.
// C: col = l&15, row = (l>>4)*4 + reg  [verified m89/m91 mapping].
// Also initializes deg[n] = 1.0 (self-loop weight).
// ---------------------------------------------------------------------------
__global__ __launch_bounds__(256) void k_gemm_mfma(
    const float* __restrict__ x, const float* __restrict__ W,
    const float* __restrict__ bl, __half* __restrict__ hn,
    float* __restrict__ deg, int N) {
  __shared__ _Float16 wsh[128 * 128];  // 32 KB, swizzled
  const int tid = threadIdx.x;
  const int wv = tid >> 6, lane = tid & 63;
  const int nb = blockIdx.x * 64;
  if (tid < 64 && nb + tid < N) deg[nb + tid] = 1.0f;

  // stage + convert W: 2048 chunks of 16B (8 halves); coalesced 32B/thread
  for (int i = tid; i < 2048; i += 256) {
    int row = i >> 4, cc = i & 15;
    const float4* wr = (const float4*)(W + row * 128 + cc * 8);
    float4 a = wr[0], b = wr[1];
    half8 h;
    h[0] = (_Float16)a.x; h[1] = (_Float16)a.y;
    h[2] = (_Float16)a.z; h[3] = (_Float16)a.w;
    h[4] = (_Float16)b.x; h[5] = (_Float16)b.y;
    h[6] = (_Float16)b.z; h[7] = (_Float16)b.w;
    *(half8*)((char*)wsh + row * 256 + ((cc * 16) ^ ((row & 7) << 4))) = h;
  }
  __syncthreads();

  const int row0 = nb + wv * 16;
  if (row0 >= N) return;  // after barrier; N%16==0 -> wave-granular guard

  const int r = lane & 15;  // A-row / B-col / C-col within tile
  const int g = lane >> 4;  // k-group (operands), row-group (C)

  // A fragments for 4 k-steps (32 floats -> 32 halves in-reg)
  half8 afrag[4];
  {
    const float4* xr = (const float4*)(x + (size_t)(row0 + r) * 128);
#pragma unroll
    for (int ks = 0; ks < 4; ++ks) {
      float4 lo = xr[ks * 8 + g * 2];
      float4 hi = xr[ks * 8 + g * 2 + 1];
      half8 a;
      a[0] = (_Float16)lo.x; a[1] = (_Float16)lo.y;
      a[2] = (_Float16)lo.z; a[3] = (_Float16)lo.w;
      a[4] = (_Float16)hi.x; a[5] = (_Float16)hi.y;
      a[6] = (_Float16)hi.z; a[7] = (_Float16)hi.w;
      afrag[ks] = a;
    }
  }

  f32x4 acc[8];
#pragma unroll
  for (int c = 0; c < 8; ++c) acc[c] = (f32x4){0.f, 0.f, 0.f, 0.f};
#pragma unroll
  for (int c = 0; c < 8; ++c) {
    const char* base = (const char*)wsh + (c * 16 + r) * 256;
    const int sw = ((c * 16 + r) & 7) << 4;
#pragma unroll
    for (int ks = 0; ks < 4; ++ks) {
      half8 b = *(const half8*)(base + ((ks * 64 + g * 16) ^ sw));
      acc[c] = __builtin_amdgcn_mfma_f32_16x16x32_f16(afrag[ks], b, acc[c],
                                                      0, 0, 0);
    }
  }

  // epilogue: bias + tanh, row sum-of-squares, normalize, fp16 store
  float t[8][4];
  float ss[4] = {0.f, 0.f, 0.f, 0.f};
#pragma unroll
  for (int c = 0; c < 8; ++c) {
    float bv = bl[c * 16 + r];
#pragma unroll
    for (int j = 0; j < 4; ++j) {
      float tv = tanh_fast(acc[c][j] + bv);
      t[c][j] = tv;
      ss[j] = fmaf(tv, tv, ss[j]);
    }
  }
#pragma unroll
  for (int j = 0; j < 4; ++j) {
#pragma unroll
    for (int off = 8; off; off >>= 1) ss[j] += __shfl_xor(ss[j], off);
    ss[j] = 1.0f / fmaxf(sqrtf(ss[j]), 1e-8f);
  }
#pragma unroll
  for (int c = 0; c < 8; ++c)
#pragma unroll
    for (int j = 0; j < 4; ++j)
      hn[(size_t)(row0 + g * 4 + j) * 128 + c * 16 + r] =
          __float2half_rn(t[c][j] * ss[j]);
}

// ---------------------------------------------------------------------------
// Stage 2: edge cosine = dot of normalized fp16 rows -> relu -> ew, fused
// with degree scatter (atomicAdd of ew into deg[col]).
// 8 lanes per edge; each lane loads 2x float4 (=16 halves) from each row.
// ---------------------------------------------------------------------------
__device__ __forceinline__ float dot8h(float4 a, float4 b) {
  const __half2* pa = (const __half2*)&a;
  const __half2* pb = (const __half2*)&b;
  float s = 0.0f;
#pragma unroll
  for (int i = 0; i < 4; ++i) {
    float2 fa = __half22float2(pa[i]);
    float2 fb = __half22float2(pb[i]);
    s = fmaf(fa.x, fb.x, s);
    s = fmaf(fa.y, fb.y, s);
  }
  return s;
}

__global__ __launch_bounds__(256) void k_edge_cos(
    const __half* __restrict__ hn, const int* __restrict__ rows,
    const int* __restrict__ cols, float* __restrict__ ew,
    float* __restrict__ deg, int E) {
  int t = blockIdx.x * 256 + threadIdx.x;
  int e = t >> 3, sub = t & 7;
  if (e >= E) return;
  int r = rows[e], c = cols[e];
  const float4* hr = (const float4*)(hn + (size_t)r * 128);  // 16 float4/row
  const float4* hc = (const float4*)(hn + (size_t)c * 128);
  float4 a0 = hr[sub], a1 = hr[sub + 8];
  float4 b0 = hc[sub], b1 = hc[sub + 8];
  float dot = dot8h(a0, b0) + dot8h(a1, b1);
#pragma unroll
  for (int off = 4; off; off >>= 1) dot += __shfl_xor(dot, off);
  if (sub == 0) {
    float w = fmaxf(dot, 0.0f);
    ew[e] = w;
    atomicAdd(deg + c, w);
  }
}

// ---------------------------------------------------------------------------
// Propagation kernels (feature dim = 1).
// Fused: per-node prep (self_norm, h0, f, agg init) + per-edge norm.
// deg >= 1 always (self-loop), so dinv = rsqrt(deg) unconditionally.
// ---------------------------------------------------------------------------
__global__ void k_prep_norm(const int* __restrict__ rows,
                            const int* __restrict__ cols,
                            const float* __restrict__ ew,
                            const float* __restrict__ deg,
                            const float* __restrict__ mask,
                            float* __restrict__ self_norm,
                            float* __restrict__ h0, float* __restrict__ f,
                            float* __restrict__ agg,
                            float* __restrict__ norm_e, int N, int E) {
  int i = blockIdx.x * 256 + threadIdx.x;
  if (i < N) {
    float d = deg[i];
    float sn = 1.0f / d;  // dinv^2
    self_norm[i] = sn;
    float h0v = fmaxf(mask[i], 0.0f);
    h0[i] = h0v;
    f[i] = h0v;
    agg[i] = sn * h0v;  // self-loop contribution for iteration 0
  }
  if (i < E) {
    float dr = deg[rows[i]], dc = deg[cols[i]];
    norm_e[i] = ew[i] * rsqrtf(dr) * rsqrtf(dc);
  }
}

__global__ void k_scatter(const int* __restrict__ rows,
                          const int* __restrict__ cols,
                          const float* __restrict__ norm_e,
                          const float* __restrict__ f,
                          float* __restrict__ agg, int E) {
  int e = blockIdx.x * 256 + threadIdx.x;
  if (e < E) atomicAdd(agg + cols[e], norm_e[e] * f[rows[e]]);
}

// f_new = (1-alpha)*agg + alpha*h0 ; non-last: agg := self_norm*f_new (prep
// next iteration); last: fill = tanh(f_new - softplus(bias)) -> d_out.
__global__ void k_update(float* __restrict__ f, float* __restrict__ agg,
                         const float* __restrict__ h0,
                         const float* __restrict__ self_norm,
                         const float* __restrict__ alpha_p,
                         const float* __restrict__ bias_p,
                         float* __restrict__ fill, int N, int last) {
  int n = blockIdx.x * 256 + threadIdx.x;
  if (n >= N) return;
  float a = alpha_p[0];
  float fn = (1.0f - a) * agg[n] + a * h0[n];
  if (last) {
    float b = bias_p[0];
    float sp = (b > 20.0f) ? b : log1pf(expf(b));
    fill[n] = tanhf(fn - sp);
  } else {
    f[n] = fn;
    agg[n] = self_norm[n] * fn;
  }
}

// ---------------------------------------------------------------------------
extern "C" void kernel_launch(void* const* d_in, const int* in_sizes, int n_in,
                              void* d_out, int out_size, void* d_ws,
                              size_t ws_size, hipStream_t stream) {
  const float* x = (const float*)d_in[0];
  const float* mask = (const float*)d_in[1];
  const int* ei = (const int*)d_in[2];  // [2, E] int32 (jax x64 disabled)
  const float* W = (const float*)d_in[3];
  const float* bl = (const float*)d_in[4];
  const float* alpha = (const float*)d_in[5];
  const float* bias = (const float*)d_in[6];

  const int D = 128;
  const int N = in_sizes[0] / D;  // 50000
  const int E = in_sizes[2] / 2;  // 600000
  const int* rows = ei;
  const int* cols = ei + E;

  float* fill = (float*)d_out;    // [N]
  float* ew = (float*)d_out + N;  // [E] edge_weights output slice

  // workspace carve-up (256B aligned)
  char* w = (char*)d_ws;
  size_t off = 0;
  auto alloc = [&](size_t bytes) -> void* {
    void* p = (void*)(w + off);
    off = (off + bytes + 255) & ~(size_t)255;
    return p;
  };
  __half* hn = (__half*)alloc((size_t)N * D * sizeof(__half));  // 12.8 MB
  float* deg = (float*)alloc((size_t)N * sizeof(float));
  float* self_norm = (float*)alloc((size_t)N * sizeof(float));
  float* h0 = (float*)alloc((size_t)N * sizeof(float));
  float* f = (float*)alloc((size_t)N * sizeof(float));
  float* agg = (float*)alloc((size_t)N * sizeof(float));
  float* norm_e = (float*)alloc((size_t)E * sizeof(float));
  (void)ws_size;

  const int nb_N = (N + 255) / 256;
  const int nb_E = (E + 255) / 256;

  // 1. MFMA GEMM (W->LDS f16) + tanh + normalize + fp16 store (+ deg=1 init)
  k_gemm_mfma<<<(N + 63) / 64, 256, 0, stream>>>(x, W, bl, hn, deg, N);
  // 2. edge cosine -> edge_weights (d_out slice), fused degree scatter
  k_edge_cos<<<(E * 8 + 255) / 256, 256, 0, stream>>>(hn, rows, cols, ew, deg,
                                                      E);
  // 3. fused node-prep + per-edge norm
  k_prep_norm<<<nb_E, 256, 0, stream>>>(rows, cols, ew, deg, mask, self_norm,
                                        h0, f, agg, norm_e, N, E);
  // 4. K=5 APPNP iterations
  for (int it = 0; it < 5; ++it) {
    k_scatter<<<nb_E, 256, 0, stream>>>(rows, cols, norm_e, f, agg, E);
    k_update<<<nb_N, 256, 0, stream>>>(f, agg, h0, self_norm, alpha, bias,
                                       fill, N, it == 4 ? 1 : 0);
  }
}

// Round 5
// 175.679 us; speedup vs baseline: 2.0713x; 1.4434x over previous
//
#include <hip/hip_runtime.h>
#include <hip/hip_bf16.h>
#include <hip/hip_fp16.h>
#include <math.h>

typedef _Float16 half8 __attribute__((ext_vector_type(8)));
typedef float f32x4 __attribute__((ext_vector_type(4)));

__device__ __forceinline__ float tanh_fast(float v) {
  // tanh(v) = 1 - 2/(exp(2v)+1); saturates correctly (exp->inf => 1, ->0 => -1)
  float e = __expf(v + v);
  return 1.0f - 2.0f * __builtin_amdgcn_rcpf(e + 1.0f);
}

// ---------------------------------------------------------------------------
// Stage 1 (MFMA): h = tanh(x @ W^T + b_lin), row-normalized, stored fp16.
// W fp32->f16 into a 32KB XOR-swizzled LDS tile (byte ^= (row&7)<<4):
// ds_read_b128 conflict-free. 4 waves/block, 16 rows x 128 cols per wave via
// mfma_f32_16x16x32_f16. C mapping: col=l&15, row=(l>>4)*4+reg [m89/m91].
// ---------------------------------------------------------------------------
__global__ __launch_bounds__(256) void k_gemm_mfma(
    const float* __restrict__ x, const float* __restrict__ W,
    const float* __restrict__ bl, __half* __restrict__ hn, int N) {
  __shared__ _Float16 wsh[128 * 128];  // 32 KB, swizzled
  const int tid = threadIdx.x;
  const int wv = tid >> 6, lane = tid & 63;
  const int nb = blockIdx.x * 64;

  for (int i = tid; i < 2048; i += 256) {
    int row = i >> 4, cc = i & 15;
    const float4* wr = (const float4*)(W + row * 128 + cc * 8);
    float4 a = wr[0], b = wr[1];
    half8 h;
    h[0] = (_Float16)a.x; h[1] = (_Float16)a.y;
    h[2] = (_Float16)a.z; h[3] = (_Float16)a.w;
    h[4] = (_Float16)b.x; h[5] = (_Float16)b.y;
    h[6] = (_Float16)b.z; h[7] = (_Float16)b.w;
    *(half8*)((char*)wsh + row * 256 + ((cc * 16) ^ ((row & 7) << 4))) = h;
  }
  __syncthreads();

  const int row0 = nb + wv * 16;
  if (row0 >= N) return;  // after barrier; N%16==0 -> wave-granular guard

  const int r = lane & 15;  // A-row / B-col / C-col within tile
  const int g = lane >> 4;  // k-group (operands), row-group (C)

  half8 afrag[4];
  {
    const float4* xr = (const float4*)(x + (size_t)(row0 + r) * 128);
#pragma unroll
    for (int ks = 0; ks < 4; ++ks) {
      float4 lo = xr[ks * 8 + g * 2];
      float4 hi = xr[ks * 8 + g * 2 + 1];
      half8 a;
      a[0] = (_Float16)lo.x; a[1] = (_Float16)lo.y;
      a[2] = (_Float16)lo.z; a[3] = (_Float16)lo.w;
      a[4] = (_Float16)hi.x; a[5] = (_Float16)hi.y;
      a[6] = (_Float16)hi.z; a[7] = (_Float16)hi.w;
      afrag[ks] = a;
    }
  }

  f32x4 acc[8];
#pragma unroll
  for (int c = 0; c < 8; ++c) acc[c] = (f32x4){0.f, 0.f, 0.f, 0.f};
#pragma unroll
  for (int c = 0; c < 8; ++c) {
    const char* base = (const char*)wsh + (c * 16 + r) * 256;
    const int sw = ((c * 16 + r) & 7) << 4;
#pragma unroll
    for (int ks = 0; ks < 4; ++ks) {
      half8 b = *(const half8*)(base + ((ks * 64 + g * 16) ^ sw));
      acc[c] = __builtin_amdgcn_mfma_f32_16x16x32_f16(afrag[ks], b, acc[c],
                                                      0, 0, 0);
    }
  }

  float t[8][4];
  float ss[4] = {0.f, 0.f, 0.f, 0.f};
#pragma unroll
  for (int c = 0; c < 8; ++c) {
    float bv = bl[c * 16 + r];
#pragma unroll
    for (int j = 0; j < 4; ++j) {
      float tv = tanh_fast(acc[c][j] + bv);
      t[c][j] = tv;
      ss[j] = fmaf(tv, tv, ss[j]);
    }
  }
#pragma unroll
  for (int j = 0; j < 4; ++j) {
#pragma unroll
    for (int off = 8; off; off >>= 1) ss[j] += __shfl_xor(ss[j], off);
    ss[j] = 1.0f / fmaxf(sqrtf(ss[j]), 1e-8f);
  }
#pragma unroll
  for (int c = 0; c < 8; ++c)
#pragma unroll
    for (int j = 0; j < 4; ++j)
      hn[(size_t)(row0 + g * 4 + j) * 128 + c * 16 + r] =
          __float2half_rn(t[c][j] * ss[j]);
}

// ---------------------------------------------------------------------------
// CSR construction (col-sorted). N < 65536 so row/col pack into one u32.
// ---------------------------------------------------------------------------
__global__ void k_init_count(const int* __restrict__ cols,
                             const float* __restrict__ mask,
                             int* __restrict__ cnt, float* __restrict__ h0,
                             float* __restrict__ f_a, int N, int E) {
  int i = blockIdx.x * 256 + threadIdx.x;
  if (i < E) atomicAdd(cnt + cols[i], 1);
  if (i < N) {
    float v = fmaxf(mask[i], 0.0f);
    h0[i] = v;
    f_a[i] = v;
  }
}

__global__ __launch_bounds__(256) void k_scan_a(const int* __restrict__ cnt,
                                                int* __restrict__ bsum,
                                                int N) {
  __shared__ int s[256];
  int i = blockIdx.x * 256 + threadIdx.x;
  s[threadIdx.x] = (i < N) ? cnt[i] : 0;
  __syncthreads();
  for (int d = 128; d; d >>= 1) {
    if (threadIdx.x < d) s[threadIdx.x] += s[threadIdx.x + d];
    __syncthreads();
  }
  if (threadIdx.x == 0) bsum[blockIdx.x] = s[0];
}

// exclusive scan of <=256 block sums (single block)
__global__ __launch_bounds__(256) void k_scan_b(const int* __restrict__ bsum,
                                                int* __restrict__ bpre,
                                                int NB) {
  __shared__ int s[2][256];
  int t = threadIdx.x;
  int v = (t < NB) ? bsum[t] : 0;
  s[0][t] = v;
  __syncthreads();
  int a = 0;
  for (int d = 1; d < 256; d <<= 1) {
    int x = s[a][t];
    if (t >= d) x += s[a][t - d];
    s[a ^ 1][t] = x;
    __syncthreads();
    a ^= 1;
  }
  bpre[t] = s[a][t] - v;  // exclusive
}

__global__ __launch_bounds__(256) void k_scan_c(
    const int* __restrict__ cnt, const int* __restrict__ bpre,
    int* __restrict__ off, int* __restrict__ cursor, int N, int E) {
  __shared__ int s[2][256];
  int t = threadIdx.x;
  int i = blockIdx.x * 256 + t;
  int v = (i < N) ? cnt[i] : 0;
  s[0][t] = v;
  __syncthreads();
  int a = 0;
  for (int d = 1; d < 256; d <<= 1) {
    int x = s[a][t];
    if (t >= d) x += s[a][t - d];
    s[a ^ 1][t] = x;
    __syncthreads();
    a ^= 1;
  }
  int excl = s[a][t] - v + bpre[blockIdx.x];
  if (i < N) {
    off[i] = excl;
    cursor[i] = excl;
  }
  if (i == 0) off[N] = E;
}

__global__ void k_build(const int* __restrict__ rows,
                        const int* __restrict__ cols, int* __restrict__ cursor,
                        uint2* __restrict__ rec, int E) {
  int e = blockIdx.x * 256 + threadIdx.x;
  if (e >= E) return;
  unsigned r = (unsigned)rows[e], c = (unsigned)cols[e];
  int pos = atomicAdd(cursor + c, 1);
  rec[pos] = make_uint2(r | (c << 16), (unsigned)e);
}

// ---------------------------------------------------------------------------
// Stage 2: edge cosine in col-sorted order. hn[col] is L1-hot (consecutive
// pos share col); hn[row] random. Writes ew[e] (output, scattered) and the
// raw weight sequentially to csr_w[pos] (for deg + propagation).
// 8 lanes per edge.
// ---------------------------------------------------------------------------
__device__ __forceinline__ float dot8h(float4 a, float4 b) {
  const __half2* pa = (const __half2*)&a;
  const __half2* pb = (const __half2*)&b;
  float s = 0.0f;
#pragma unroll
  for (int i = 0; i < 4; ++i) {
    float2 fa = __half22float2(pa[i]);
    float2 fb = __half22float2(pb[i]);
    s = fmaf(fa.x, fb.x, s);
    s = fmaf(fa.y, fb.y, s);
  }
  return s;
}

__global__ __launch_bounds__(256) void k_edge_cos(
    const __half* __restrict__ hn, const uint2* __restrict__ rec,
    float* __restrict__ ew, float* __restrict__ csr_w, int E) {
  int t = blockIdx.x * 256 + threadIdx.x;
  int pos = t >> 3, sub = t & 7;
  if (pos >= E) return;
  uint2 rc = rec[pos];
  unsigned row = rc.x & 0xffffu, col = rc.x >> 16;
  const float4* hr = (const float4*)(hn + (size_t)row * 128);
  const float4* hc = (const float4*)(hn + (size_t)col * 128);
  float4 a0 = hr[sub], a1 = hr[sub + 8];
  float4 b0 = hc[sub], b1 = hc[sub + 8];
  float dot = dot8h(a0, b0) + dot8h(a1, b1);
#pragma unroll
  for (int off = 4; off; off >>= 1) dot += __shfl_xor(dot, off);
  if (sub == 0) {
    float w = fmaxf(dot, 0.0f);
    ew[rc.y] = w;
    csr_w[pos] = w;
  }
}

// deg[n] = 1 + sum of raw weights in n's segment (deterministic); rsd=rsqrt
__global__ void k_deg(const float* __restrict__ csr_w,
                      const int* __restrict__ off, float* __restrict__ rsd,
                      int N) {
  int n = blockIdx.x * 256 + threadIdx.x;
  if (n >= N) return;
  int s0 = off[n], s1 = off[n + 1];
  float s = 1.0f;
  for (int i = s0; i < s1; ++i) s += csr_w[i];
  rsd[n] = rsqrtf(s);
}

// scale csr_w in place by rsd[row]*rsd[col]; emit u16 src array
__global__ void k_wcsr(const uint2* __restrict__ rec,
                       float* __restrict__ csr_w,
                       const float* __restrict__ rsd,
                       unsigned short* __restrict__ src16, int E) {
  int p = blockIdx.x * 256 + threadIdx.x;
  if (p >= E) return;
  unsigned rc = rec[p].x;
  unsigned row = rc & 0xffffu, col = rc >> 16;
  csr_w[p] *= rsd[row] * rsd[col];
  src16[p] = (unsigned short)row;
}

// ---------------------------------------------------------------------------
// One APPNP iteration, fused gather-reduce + update. No atomics.
// f_next[n] = (1-a)*(self + sum_seg csr_w*f[src]) + a*h0[n]
// last iteration writes fill = tanh(f - softplus(bias)) to d_out.
// ---------------------------------------------------------------------------
__global__ void k_prop(const float* __restrict__ f_in, float* __restrict__ f_out,
                       const float* __restrict__ csr_w,
                       const unsigned short* __restrict__ src16,
                       const int* __restrict__ off, const float* __restrict__ h0,
                       const float* __restrict__ rsd,
                       const float* __restrict__ alpha_p,
                       const float* __restrict__ bias_p,
                       float* __restrict__ fill, int N, int last) {
  int n = blockIdx.x * 256 + threadIdx.x;
  if (n >= N) return;
  float a = alpha_p[0];
  float rs = rsd[n];
  float agg = f_in[n] * rs * rs;  // self-loop: norm = 1/deg
  int s0 = off[n], s1 = off[n + 1];
  for (int i = s0; i < s1; ++i)
    agg = fmaf(csr_w[i], f_in[src16[i]], agg);
  float fn = (1.0f - a) * agg + a * h0[n];
  if (last) {
    float b = bias_p[0];
    float sp = (b > 20.0f) ? b : log1pf(expf(b));
    fill[n] = tanhf(fn - sp);
  } else {
    f_out[n] = fn;
  }
}

// ---------------------------------------------------------------------------
extern "C" void kernel_launch(void* const* d_in, const int* in_sizes, int n_in,
                              void* d_out, int out_size, void* d_ws,
                              size_t ws_size, hipStream_t stream) {
  const float* x = (const float*)d_in[0];
  const float* mask = (const float*)d_in[1];
  const int* ei = (const int*)d_in[2];  // [2, E] int32 (jax x64 disabled)
  const float* W = (const float*)d_in[3];
  const float* bl = (const float*)d_in[4];
  const float* alpha = (const float*)d_in[5];
  const float* bias = (const float*)d_in[6];

  const int D = 128;
  const int N = in_sizes[0] / D;  // 50000  (< 65536: u16 node ids)
  const int E = in_sizes[2] / 2;  // 600000
  const int* rows = ei;
  const int* cols = ei + E;

  float* fill = (float*)d_out;    // [N]
  float* ew = (float*)d_out + N;  // [E] edge_weights output slice

  // workspace carve-up (256B aligned)
  char* w = (char*)d_ws;
  size_t off_b = 0;
  auto alloc = [&](size_t bytes) -> void* {
    void* p = (void*)(w + off_b);
    off_b = (off_b + bytes + 255) & ~(size_t)255;
    return p;
  };
  __half* hn = (__half*)alloc((size_t)N * D * sizeof(__half));  // 12.8 MB
  int* cnt = (int*)alloc((size_t)N * sizeof(int));
  int* off = (int*)alloc((size_t)(N + 1) * sizeof(int));
  int* cursor = (int*)alloc((size_t)N * sizeof(int));
  int* bsum = (int*)alloc(256 * sizeof(int));
  int* bpre = (int*)alloc(256 * sizeof(int));
  uint2* rec = (uint2*)alloc((size_t)E * sizeof(uint2));        // 4.8 MB
  float* csr_w = (float*)alloc((size_t)E * sizeof(float));      // 2.4 MB
  unsigned short* src16 =
      (unsigned short*)alloc((size_t)E * sizeof(unsigned short));
  float* h0 = (float*)alloc((size_t)N * sizeof(float));
  float* f_a = (float*)alloc((size_t)N * sizeof(float));
  float* f_b = (float*)alloc((size_t)N * sizeof(float));
  float* rsd = (float*)alloc((size_t)N * sizeof(float));
  (void)ws_size;

  const int NB_N = (N + 255) / 256;  // 196 <= 256 (scan_b capacity)
  const int nb_E = (E + 255) / 256;

  hipMemsetAsync(cnt, 0, (size_t)N * sizeof(int), stream);
  // histogram cols + node inits (h0, f_a)
  k_init_count<<<nb_E, 256, 0, stream>>>(cols, mask, cnt, h0, f_a, N, E);
  // MFMA GEMM + tanh + normalize + fp16 store
  k_gemm_mfma<<<(N + 63) / 64, 256, 0, stream>>>(x, W, bl, hn, N);
  // exclusive scan of cnt -> off, cursor
  k_scan_a<<<NB_N, 256, 0, stream>>>(cnt, bsum, N);
  k_scan_b<<<1, 256, 0, stream>>>(bsum, bpre, NB_N);
  k_scan_c<<<NB_N, 256, 0, stream>>>(cnt, bpre, off, cursor, N, E);
  // col-sorted edge records
  k_build<<<nb_E, 256, 0, stream>>>(rows, cols, cursor, rec, E);
  // cosine in sorted order -> ew (scattered) + csr_w (sequential)
  k_edge_cos<<<(E * 8 + 255) / 256, 256, 0, stream>>>(hn, rec, ew, csr_w, E);
  // deterministic segmented degree + rsqrt
  k_deg<<<NB_N, 256, 0, stream>>>(csr_w, off, rsd, N);
  // normalize csr weights, emit u16 src
  k_wcsr<<<nb_E, 256, 0, stream>>>(rec, csr_w, rsd, src16, E);
  // K=5 APPNP iterations (gather-reduce, fused update)
  const float* fi = f_a;
  float* fo = f_b;
  for (int it = 0; it < 5; ++it) {
    k_prop<<<NB_N, 256, 0, stream>>>(fi, fo, csr_w, src16, off, h0, rsd,
                                     alpha, bias, fill, N, it == 4 ? 1 : 0);
    const float* tmp = fo;
    fo = (float*)fi;
    fi = tmp;
  }
}